// Round 6
// baseline (389.487 us; speedup 1.0000x reference)
//
#include <hip/hip_runtime.h>
#include <stdint.h>

typedef unsigned int  uint32;
typedef unsigned short u16;

typedef short bfx8 __attribute__((ext_vector_type(8)));
typedef float f32x4 __attribute__((ext_vector_type(4)));
typedef uint32 u32x2 __attribute__((ext_vector_type(2)));

#define NBP 256          // padded bucket count (N <= 65536)
#define CH  2048         // edges per partition chunk
#define BS  4608         // fixed slots per bucket (mean 4096, sigma~64 -> 8-sigma margin)

// Feature layout for ALL activation buffers: 2 planes [2][N][64] bf16.
// Plane = 6.4 MB -> per-XCD L2 (4 MiB) hit rate ~2x vs unsplit 12.8 MB table.
// Gather kernels walk plane p = (blk >= G1); r2 wave structure preserved:
// 4 groups x 16 lanes, 4 loads/lane in flight, 2-stage shuffle (16 shfl/node total).

// ---------- bf16 helpers ----------
__device__ __forceinline__ float b2f(u16 u) {
    union { uint32 i; float f; } v; v.i = ((uint32)u) << 16; return v.f;
}
__device__ __forceinline__ u16 f2b(float f) {
    union { float f; uint32 i; } v; v.f = f;
    uint32 u = v.i;
    return (u16)((u + 0x7fffu + ((u >> 16) & 1u)) >> 16);   // RNE
}
__device__ __forceinline__ float blo(uint32 u) {
    union { uint32 i; float f; } v; v.i = u << 16; return v.f;
}
__device__ __forceinline__ float bhi(uint32 u) {
    union { uint32 i; float f; } v; v.i = u & 0xffff0000u; return v.f;
}
__device__ __forceinline__ uint32 packbf(float a, float b) {
    return (uint32)f2b(a) | ((uint32)f2b(b) << 16);
}
__device__ __forceinline__ void splitf(float x, u16& h, u16& l) {
    h = f2b(x);
    l = f2b(x - b2f(h));
}
// accumulate an 8-byte chunk (2 packed bf16-pairs) into 4 fp32 sums
__device__ __forceinline__ void acc2(float* s, u32x2 v) {
    s[0] += blo(v.x); s[1] += bhi(v.x);
    s[2] += blo(v.y); s[3] += bhi(v.y);
}
// fused-scale accumulate: s += d * v
__device__ __forceinline__ void acc2f(float* s, u32x2 v, float d) {
    s[0] = fmaf(blo(v.x), d, s[0]); s[1] = fmaf(bhi(v.x), d, s[1]);
    s[2] = fmaf(blo(v.y), d, s[2]); s[3] = fmaf(bhi(v.y), d, s[3]);
}

// ---------- init: block 0 sets bucket cursors; other blocks split weights ----------
__global__ __launch_bounds__(256) void k_init(
    int* __restrict__ curC, int* __restrict__ curR,
    const float* __restrict__ W1, const float* __restrict__ W2,
    const float* __restrict__ W3, const float* __restrict__ fcW,
    u16* __restrict__ WTh, u16* __restrict__ WTl, int WTN) {
    int t = threadIdx.x;
    if (blockIdx.x == 0) {
        curC[t] = t * BS;
        curR[t] = t * BS;
        return;
    }
    int i = ((int)blockIdx.x - 1) * 256 + t;
    if (i >= WTN) return;
    float w;
    if (i < 3 * 16384) {
        int m = i >> 14, j = i & 16383;     // j = fo*128 + fi
        int fo = j >> 7, fi = j & 127;
        const float* W = (m == 0) ? W1 : (m == 1) ? W2 : W3;
        w = W[fi * 128 + fo];
    } else {
        int j = i - 3 * 16384;
        int fo = j >> 7, fi = j & 127;
        w = fcW[fi * 64 + fo];
    }
    u16 h, l; splitf(w, h, l);
    WTh[i] = h; WTl[i] = l;
}

// ---------- pass C: dual-direction bucket partition into fixed-stride regions ---------
__global__ __launch_bounds__(256) void k_partC(
    const int* __restrict__ row, const int* __restrict__ col, int E,
    int* __restrict__ curC, int* __restrict__ curR,
    uint32* __restrict__ partC, uint32* __restrict__ partR) {
    __shared__ uint32 stagedC[CH], stagedR[CH];
    __shared__ int hp[NBP], expk[NBP], curp[NBP], runC[NBP], runR[NBP];
    __shared__ int wsum[4];
    int t = threadIdx.x;
    int lane = t & 63, wid = t >> 6;
    int base = blockIdx.x * CH;
    int n = E - base; if (n > CH) n = CH;

    int er[8], ec[8];
#pragma unroll
    for (int j = 0; j < 8; ++j) {
        int i = t + j * 256;
        if (i < n) { er[j] = row[base + i]; ec[j] = col[base + i]; }
        else er[j] = -1;
    }
    hp[t] = 0;
    __syncthreads();
#pragma unroll
    for (int j = 0; j < 8; ++j) {
        if (er[j] >= 0) {
            atomicAdd(&hp[ec[j] >> 8], 1);
            atomicAdd(&hp[er[j] >> 8], 0x10000);
        }
    }
    __syncthreads();
    int v = hp[t];
    int x = v;
#pragma unroll
    for (int d = 1; d < 64; d <<= 1) {
        int u = __shfl_up(x, d);
        if (lane >= d) x += u;
    }
    if (lane == 63) wsum[wid] = x;
    __syncthreads();
    int add = 0;
    for (int i = 0; i < wid; ++i) add += wsum[i];
    int ex = x + add - v;
    expk[t] = ex;
    curp[t] = ex;
    int vC = v & 0xffff, vR = v >> 16;
    runC[t] = vC ? atomicAdd(&curC[t], vC) : 0;
    runR[t] = vR ? atomicAdd(&curR[t], vR) : 0;
    __syncthreads();
#pragma unroll
    for (int j = 0; j < 8; ++j) {
        if (er[j] >= 0) {
            int cb = ec[j] >> 8, rb = er[j] >> 8;
            int pC = atomicAdd(&curp[cb], 1) & 0xffff;
            stagedC[pC] = ((uint32)ec[j] << 16) | (uint32)er[j];
            int pR = atomicAdd(&curp[rb], 0x10000) >> 16;
            stagedR[pR] = ((uint32)er[j] << 16) | (uint32)ec[j];
        }
    }
    __syncthreads();
    for (int i = t; i < n; i += 256) {
        uint32 pv = stagedC[i];
        int b = pv >> 24;
        partC[runC[b] + (i - (expk[b] & 0xffff))] = pv;
    }
    for (int i = t; i < n; i += 256) {
        uint32 pv = stagedR[i];
        int b = pv >> 24;
        partR[runR[b] + (i - (expk[b] >> 16))] = pv;
    }
}

// ---------- fused dispatch: fillD blocks + gemm0 blocks (independent halves) ----------
// fillD part: per-bucket CSR fill + per-node (start,end) + dinv.
// gemm0 part: G = A @ W, bf16 out in SPLIT planes, NO dinv scale.
__global__ __launch_bounds__(256) void k_fillDg0(
    const uint32* __restrict__ partC, const uint32* __restrict__ partR,
    const int* __restrict__ curC, const int* __restrict__ curR,
    int* __restrict__ off_in, int* __restrict__ end_in,
    int* __restrict__ off_out, int* __restrict__ end_out,
    u16* __restrict__ csr_src, u16* __restrict__ csr_dst,
    float* __restrict__ dinv, int NB, int N,
    const float* __restrict__ A, const u16* __restrict__ WTh,
    const u16* __restrict__ WTl, u16* __restrict__ G) {
    __shared__ int cnt[NBP], cur[NBP];
    __shared__ int wsum[4];
    int t = threadIdx.x;

    if ((int)blockIdx.x < 2 * NB) {
        // ----- fillD half -----
        int part = ((int)blockIdx.x >= NB) ? 1 : 0;
        int b = (int)blockIdx.x - part * NB;
        const uint32* arr = part ? partR : partC;
        const int* curA   = part ? curR : curC;
        int* offA         = part ? off_out : off_in;
        int* endA         = part ? end_out : end_in;
        u16* csr          = part ? csr_dst : csr_src;
        int lane = t & 63, wid = t >> 6;
        int base = b * BS, end = curA[b];
        cnt[t] = 0;
        __syncthreads();
        for (int i = base + t; i < end; i += 256)
            atomicAdd(&cnt[(arr[i] >> 16) & 255], 1);
        __syncthreads();
        int v = cnt[t];
        int x = v;
#pragma unroll
        for (int d = 1; d < 64; d <<= 1) {
            int u = __shfl_up(x, d);
            if (lane >= d) x += u;
        }
        if (lane == 63) wsum[wid] = x;
        __syncthreads();
        int add = 0;
        for (int i = 0; i < wid; ++i) add += wsum[i];
        int ex = x + add - v;
        cur[t] = ex;
        int node = (b << 8) + t;
        if (node < N) {
            offA[node] = base + ex;
            endA[node] = base + ex + v;
            if (part == 0) dinv[node] = rsqrtf((float)(v + 1));   // in-degree + self loop
        }
        __syncthreads();
        for (int i = base + t; i < end; i += 256) {
            uint32 pv = arr[i];
            int local = (pv >> 16) & 255;
            int pos = atomicAdd(&cur[local], 1);
            csr[base + pos] = (u16)(pv & 0xffffu);
        }
        return;
    }

    // ----- gemm0 half -----
    {
        int gb = (int)blockIdx.x - 2 * NB;
        const int lane = t & 63;
        const int q = lane >> 4, l = lane & 15;
        const size_t N64 = (size_t)N * 64;
        int rbase = gb * 128 + (t >> 6) * 32;
        if (rbase >= N) return;
        int r0 = rbase + l;      if (r0 >= N) r0 = N - 1;
        int r1 = rbase + 16 + l; if (r1 >= N) r1 = N - 1;

        f32x4 acc[2][8];
#pragma unroll
        for (int i = 0; i < 2; ++i)
#pragma unroll
            for (int j = 0; j < 8; ++j) acc[i][j] = (f32x4){0.f, 0.f, 0.f, 0.f};

#pragma unroll
        for (int kc = 0; kc < 4; ++kc) {
            int k0 = kc * 32 + q * 8;
            bfx8 ah0, ah1;
            {
                f32x4 a = *(const f32x4*)(A + (size_t)r0 * 128 + k0);
                f32x4 b = *(const f32x4*)(A + (size_t)r0 * 128 + k0 + 4);
                float xx[8] = {a[0], a[1], a[2], a[3], b[0], b[1], b[2], b[3]};
#pragma unroll
                for (int j = 0; j < 8; ++j) ah0[j] = (short)f2b(xx[j]);
            }
            {
                f32x4 a = *(const f32x4*)(A + (size_t)r1 * 128 + k0);
                f32x4 b = *(const f32x4*)(A + (size_t)r1 * 128 + k0 + 4);
                float xx[8] = {a[0], a[1], a[2], a[3], b[0], b[1], b[2], b[3]};
#pragma unroll
                for (int j = 0; j < 8; ++j) ah1[j] = (short)f2b(xx[j]);
            }
#pragma unroll
            for (int ct = 0; ct < 8; ++ct) {
                bfx8 bh = *(const bfx8*)(WTh + (ct * 16 + l) * 128 + k0);
                bfx8 bl = *(const bfx8*)(WTl + (ct * 16 + l) * 128 + k0);
                acc[0][ct] = __builtin_amdgcn_mfma_f32_16x16x32_bf16(ah0, bh, acc[0][ct], 0, 0, 0);
                acc[0][ct] = __builtin_amdgcn_mfma_f32_16x16x32_bf16(ah0, bl, acc[0][ct], 0, 0, 0);
                acc[1][ct] = __builtin_amdgcn_mfma_f32_16x16x32_bf16(ah1, bh, acc[1][ct], 0, 0, 0);
                acc[1][ct] = __builtin_amdgcn_mfma_f32_16x16x32_bf16(ah1, bl, acc[1][ct], 0, 0, 0);
            }
        }
#pragma unroll
        for (int rs = 0; rs < 2; ++rs) {
#pragma unroll
            for (int rr = 0; rr < 4; ++rr) {
                int rw = rbase + rs * 16 + q * 4 + rr;
                if (rw < N) {
#pragma unroll
                    for (int ct = 0; ct < 8; ++ct)
                        G[(size_t)(ct >> 2) * N64 + (size_t)rw * 64 + (ct & 3) * 16 + l]
                            = f2b(acc[rs][ct][rr]);
                }
            }
        }
    }
}

// ---------- gemm, SPLIT bf16 A: G = (A @ W) * dinv, bf16 out in SPLIT planes ----------
__global__ __launch_bounds__(256) void k_gemm1p(
    const u16* __restrict__ Ah,
    const u16* __restrict__ WTh, const u16* __restrict__ WTl,
    const float* __restrict__ dinv, u16* __restrict__ G, int M) {
    const int lane = threadIdx.x & 63;
    const int q = lane >> 4, l = lane & 15;
    const size_t N64 = (size_t)M * 64;
    int rbase = blockIdx.x * 128 + (threadIdx.x >> 6) * 32;
    if (rbase >= M) return;
    int r0 = rbase + l;      if (r0 >= M) r0 = M - 1;
    int r1 = rbase + 16 + l; if (r1 >= M) r1 = M - 1;

    f32x4 acc[2][8];
#pragma unroll
    for (int i = 0; i < 2; ++i)
#pragma unroll
        for (int j = 0; j < 8; ++j) acc[i][j] = (f32x4){0.f, 0.f, 0.f, 0.f};

#pragma unroll
    for (int kc = 0; kc < 4; ++kc) {
        int k0 = kc * 32 + q * 8;   // weight-side K index
        size_t ao = (size_t)(kc >> 1) * N64 + (kc & 1) * 32 + q * 8;
        bfx8 ah0 = *(const bfx8*)(Ah + ao + (size_t)r0 * 64);
        bfx8 ah1 = *(const bfx8*)(Ah + ao + (size_t)r1 * 64);
#pragma unroll
        for (int ct = 0; ct < 8; ++ct) {
            bfx8 bh = *(const bfx8*)(WTh + (ct * 16 + l) * 128 + k0);
            bfx8 bl = *(const bfx8*)(WTl + (ct * 16 + l) * 128 + k0);
            acc[0][ct] = __builtin_amdgcn_mfma_f32_16x16x32_bf16(ah0, bh, acc[0][ct], 0, 0, 0);
            acc[0][ct] = __builtin_amdgcn_mfma_f32_16x16x32_bf16(ah0, bl, acc[0][ct], 0, 0, 0);
            acc[1][ct] = __builtin_amdgcn_mfma_f32_16x16x32_bf16(ah1, bh, acc[1][ct], 0, 0, 0);
            acc[1][ct] = __builtin_amdgcn_mfma_f32_16x16x32_bf16(ah1, bl, acc[1][ct], 0, 0, 0);
        }
    }
#pragma unroll
    for (int rs = 0; rs < 2; ++rs) {
#pragma unroll
        for (int rr = 0; rr < 4; ++rr) {
            int rw = rbase + rs * 16 + q * 4 + rr;
            if (rw < M) {
                float dv = dinv[rw];
#pragma unroll
                for (int ct = 0; ct < 8; ++ct)
                    G[(size_t)(ct >> 2) * N64 + (size_t)rw * 64 + (ct & 3) * 16 + l]
                        = f2b(acc[rs][ct][rr] * dv);
            }
        }
    }
}

// ---------- layer-0 GCN aggregate: UNSCALED split table, per-row dinv via fmac -------
// plane p = (blk >= G1); 4 groups x 16 lanes; lane covers 8B of the 128B plane-row.
__global__ __launch_bounds__(256) void k_agg0(
    const uint32* __restrict__ T, const u16* __restrict__ csr,
    const int* __restrict__ off, const int* __restrict__ endo,
    const float* __restrict__ dinv,
    const float* __restrict__ bias, uint32* __restrict__ outT, int n, int G1) {
    int blk = (int)blockIdx.x;
    int p = (blk >= G1) ? 1 : 0;
    int nb = blk - p * G1;
    int w = nb * 4 + (int)(threadIdx.x >> 6);
    if (w >= n) return;
    int lane = threadIdx.x & 63;
    int gq = lane >> 4, c = lane & 15;
    const uint32* Tp = T + (size_t)p * n * 32;
    float s[4] = {0.f, 0.f, 0.f, 0.f};
    int e = off[w], e1 = endo[w];
    for (; e + 16 <= e1; e += 16) {
        int ix[4];
#pragma unroll
        for (int j = 0; j < 4; ++j) ix[j] = csr[e + j * 4 + gq];
        u32x2 vv[4];
        float dd[4];
#pragma unroll
        for (int j = 0; j < 4; ++j) {
            vv[j] = *(const u32x2*)(Tp + (size_t)ix[j] * 32 + c * 2);
            dd[j] = dinv[ix[j]];
        }
#pragma unroll
        for (int j = 0; j < 4; ++j) acc2f(s, vv[j], dd[j]);
    }
    for (; e < e1; e += 4) {
        int idx = e + gq;
        if (idx < e1) {
            int ii = csr[idx];
            acc2f(s, *(const u32x2*)(Tp + (size_t)ii * 32 + c * 2), dinv[ii]);
        }
    }
#pragma unroll
    for (int k = 0; k < 4; ++k) {
        s[k] += __shfl_xor(s[k], 16);
        s[k] += __shfl_xor(s[k], 32);
    }
    if (lane < 16) {
        float dc = dinv[w];
        u32x2 sv = *(const u32x2*)(Tp + (size_t)w * 32 + lane * 2);
        acc2f(s, sv, dc);                               // self term, scale dc
        f32x4 bb = *(const f32x4*)(bias + p * 64 + lane * 4);
        float o[4];
#pragma unroll
        for (int k = 0; k < 4; ++k) o[k] = fmaxf(fmaf(s[k], dc, bb[k]), 0.f);
        u32x2 ov;
        ov.x = packbf(o[0], o[1]); ov.y = packbf(o[2], o[3]);
        *(u32x2*)(outT + (size_t)p * n * 32 + (size_t)w * 32 + lane * 2) = ov;
    }
}

// ---------- GCN aggregate (layers 1-2): PRESCALED split table ----------
__global__ __launch_bounds__(256) void k_agg(
    const uint32* __restrict__ T, const u16* __restrict__ csr,
    const int* __restrict__ off, const int* __restrict__ endo,
    const float* __restrict__ dinv,
    const float* __restrict__ bias, uint32* __restrict__ outT, int n, int G1) {
    int blk = (int)blockIdx.x;
    int p = (blk >= G1) ? 1 : 0;
    int nb = blk - p * G1;
    int w = nb * 4 + (int)(threadIdx.x >> 6);
    if (w >= n) return;
    int lane = threadIdx.x & 63;
    int gq = lane >> 4, c = lane & 15;
    const uint32* Tp = T + (size_t)p * n * 32;
    float s[4] = {0.f, 0.f, 0.f, 0.f};
    int e = off[w], e1 = endo[w];
    for (; e + 16 <= e1; e += 16) {
        int ix[4];
#pragma unroll
        for (int j = 0; j < 4; ++j) ix[j] = csr[e + j * 4 + gq];
        u32x2 vv[4];
#pragma unroll
        for (int j = 0; j < 4; ++j) vv[j] = *(const u32x2*)(Tp + (size_t)ix[j] * 32 + c * 2);
#pragma unroll
        for (int j = 0; j < 4; ++j) acc2(s, vv[j]);
    }
    for (; e < e1; e += 4) {
        int idx = e + gq;
        if (idx < e1) {
            int ii = csr[idx];
            acc2(s, *(const u32x2*)(Tp + (size_t)ii * 32 + c * 2));
        }
    }
#pragma unroll
    for (int k = 0; k < 4; ++k) {
        s[k] += __shfl_xor(s[k], 16);
        s[k] += __shfl_xor(s[k], 32);
    }
    if (lane < 16) {
        u32x2 sv = *(const u32x2*)(Tp + (size_t)w * 32 + lane * 2);
        acc2(s, sv);                                    // self term (prescaled)
        float dc = dinv[w];
        f32x4 bb = *(const f32x4*)(bias + p * 64 + lane * 4);
        float o[4];
#pragma unroll
        for (int k = 0; k < 4; ++k) o[k] = fmaxf(fmaf(s[k], dc, bb[k]), 0.f);
        u32x2 ov;
        ov.x = packbf(o[0], o[1]); ov.y = packbf(o[2], o[3]);
        *(u32x2*)(outT + (size_t)p * n * 32 + (size_t)w * 32 + lane * 2) = ov;
    }
}

// ---------- neighbor mean, split table, bf16 out ----------
__global__ __launch_bounds__(256) void k_mean(
    const uint32* __restrict__ T, const u16* __restrict__ csr,
    const int* __restrict__ off, const int* __restrict__ endo,
    uint32* __restrict__ outT, int n, int G1) {
    int blk = (int)blockIdx.x;
    int p = (blk >= G1) ? 1 : 0;
    int nb = blk - p * G1;
    int w = nb * 4 + (int)(threadIdx.x >> 6);
    if (w >= n) return;
    int lane = threadIdx.x & 63;
    int gq = lane >> 4, c = lane & 15;
    const uint32* Tp = T + (size_t)p * n * 32;
    float s[4] = {0.f, 0.f, 0.f, 0.f};
    int e = off[w], e1 = endo[w];
    int d = e1 - e;
    for (; e + 16 <= e1; e += 16) {
        int ix[4];
#pragma unroll
        for (int j = 0; j < 4; ++j) ix[j] = csr[e + j * 4 + gq];
        u32x2 vv[4];
#pragma unroll
        for (int j = 0; j < 4; ++j) vv[j] = *(const u32x2*)(Tp + (size_t)ix[j] * 32 + c * 2);
#pragma unroll
        for (int j = 0; j < 4; ++j) acc2(s, vv[j]);
    }
    for (; e < e1; e += 4) {
        int idx = e + gq;
        if (idx < e1) {
            int ii = csr[idx];
            acc2(s, *(const u32x2*)(Tp + (size_t)ii * 32 + c * 2));
        }
    }
#pragma unroll
    for (int k = 0; k < 4; ++k) {
        s[k] += __shfl_xor(s[k], 16);
        s[k] += __shfl_xor(s[k], 32);
    }
    if (lane < 16) {
        u32x2 ov;
        if (d > 0) {
            float inv = 1.f / (float)d;
            ov.x = packbf(s[0] * inv, s[1] * inv);
            ov.y = packbf(s[2] * inv, s[3] * inv);
        } else {
            ov = *(const u32x2*)(Tp + (size_t)w * 32 + lane * 2);  // degree 0: own feature
        }
        *(u32x2*)(outT + (size_t)p * n * 32 + (size_t)w * 32 + lane * 2) = ov;
    }
}

// ---------- final: out = (w0*h0 + w1*h1 + w2*h2) @ fcW + fc_b (SPLIT A) ----------
__global__ __launch_bounds__(256) void k_final(
    const u16* __restrict__ h0, const u16* __restrict__ h1,
    const u16* __restrict__ h2, const float* __restrict__ jkw,
    const u16* __restrict__ fcWTh, const u16* __restrict__ fcWTl,
    const float* __restrict__ fcb, float* __restrict__ out, int M) {
    float a0 = jkw[0], a1 = jkw[1], a2 = jkw[2];
    float mx = fmaxf(a0, fmaxf(a1, a2));
    float e0 = expf(a0 - mx), e1 = expf(a1 - mx), e2 = expf(a2 - mx);
    float inv = 1.f / (e0 + e1 + e2);
    float w0 = e0 * inv, w1 = e1 * inv, w2 = e2 * inv;

    const int lane = threadIdx.x & 63;
    const int q = lane >> 4, l = lane & 15;
    const size_t N64 = (size_t)M * 64;
    int rbase = blockIdx.x * 128 + (threadIdx.x >> 6) * 32;
    if (rbase >= M) return;
    int r0 = rbase + l;      if (r0 >= M) r0 = M - 1;
    int r1 = rbase + 16 + l; if (r1 >= M) r1 = M - 1;

    f32x4 acc[2][4];
#pragma unroll
    for (int i = 0; i < 2; ++i)
#pragma unroll
        for (int j = 0; j < 4; ++j) acc[i][j] = (f32x4){0.f, 0.f, 0.f, 0.f};

    union U8 { bfx8 v; u16 u[8]; };

#pragma unroll
    for (int kc = 0; kc < 4; ++kc) {
        int k0 = kc * 32 + q * 8;
        size_t ao = (size_t)(kc >> 1) * N64 + (kc & 1) * 32 + q * 8;
        bfx8 ah[2];
        const int rr2[2] = {r0, r1};
#pragma unroll
        for (int half = 0; half < 2; ++half) {
            size_t o = ao + (size_t)rr2[half] * 64;
            U8 x0, x1, x2, rh;
            x0.v = *(const bfx8*)(h0 + o);
            x1.v = *(const bfx8*)(h1 + o);
            x2.v = *(const bfx8*)(h2 + o);
#pragma unroll
            for (int j = 0; j < 8; ++j) {
                float c = w0 * b2f(x0.u[j]) + w1 * b2f(x1.u[j]) + w2 * b2f(x2.u[j]);
                rh.u[j] = f2b(c);
            }
            ah[half] = rh.v;
        }
#pragma unroll
        for (int ct = 0; ct < 4; ++ct) {
            bfx8 bh = *(const bfx8*)(fcWTh + (ct * 16 + l) * 128 + k0);
            bfx8 bl = *(const bfx8*)(fcWTl + (ct * 16 + l) * 128 + k0);
#pragma unroll
            for (int half = 0; half < 2; ++half) {
                acc[half][ct] = __builtin_amdgcn_mfma_f32_16x16x32_bf16(ah[half], bh, acc[half][ct], 0, 0, 0);
                acc[half][ct] = __builtin_amdgcn_mfma_f32_16x16x32_bf16(ah[half], bl, acc[half][ct], 0, 0, 0);
            }
        }
    }
#pragma unroll
    for (int rs = 0; rs < 2; ++rs) {
#pragma unroll
        for (int rr = 0; rr < 4; ++rr) {
            int rw = rbase + rs * 16 + q * 4 + rr;
            if (rw < M) {
#pragma unroll
                for (int ct = 0; ct < 4; ++ct) {
                    int cc = ct * 16 + l;
                    out[(size_t)rw * 64 + cc] = acc[rs][ct][rr] + fcb[cc];
                }
            }
        }
    }
}

extern "C" void kernel_launch(void* const* d_in, const int* in_sizes, int n_in,
                              void* d_out, int out_size, void* d_ws, size_t ws_size,
                              hipStream_t stream) {
    const int N = in_sizes[0] / 128;   // 50000
    const int E = in_sizes[1] / 2;     // 800000
    const int NB = (N + 255) >> 8;     // 196 buckets

    const float* x    = (const float*)d_in[0];
    const int* row    = (const int*)d_in[1];
    const int* col    = row + E;
    const float* W1   = (const float*)d_in[2];
    const float* b1   = (const float*)d_in[3];
    const float* W2   = (const float*)d_in[4];
    const float* b2   = (const float*)d_in[5];
    const float* W3   = (const float*)d_in[6];
    const float* b3   = (const float*)d_in[7];
    const float* jkw  = (const float*)d_in[8];
    const float* fcW  = (const float*)d_in[9];
    const float* fcb  = (const float*)d_in[10];
    float* outp       = (float*)d_out;

    char* ws = (char*)d_ws;
    size_t off = 0;
    auto alloc = [&](size_t bytes) -> char* {
        char* p = ws + off;
        off += (bytes + 255) & ~(size_t)255;
        return p;
    };
    int* curC   = (int*)alloc((size_t)NBP * sizeof(int));
    int* curR   = (int*)alloc((size_t)NBP * sizeof(int));
    int* off_in  = (int*)alloc((size_t)N * sizeof(int));
    int* end_in  = (int*)alloc((size_t)N * sizeof(int));
    int* off_out = (int*)alloc((size_t)N * sizeof(int));
    int* end_out = (int*)alloc((size_t)N * sizeof(int));
    uint32* partC = (uint32*)alloc((size_t)NBP * BS * sizeof(uint32));
    uint32* partR = (uint32*)alloc((size_t)NBP * BS * sizeof(uint32));
    u16* csr_src = (u16*)alloc((size_t)NBP * BS * sizeof(u16));
    u16* csr_dst = (u16*)alloc((size_t)NBP * BS * sizeof(u16));
    float* dinv  = (float*)alloc((size_t)N * sizeof(float));
    const int WTN = 3 * 16384 + 8192;
    u16* WTh = (u16*)alloc((size_t)WTN * sizeof(u16));
    u16* WTl = (u16*)alloc((size_t)WTN * sizeof(u16));
    size_t FB = (size_t)N * 128 * sizeof(u16);
    u16* gbuf = (u16*)alloc(FB);     // all feature buffers: SPLIT [2][N][64] bf16
    u16* t0   = (u16*)alloc(FB);
    u16* h0   = (u16*)alloc(FB);
    u16* h1   = (u16*)alloc(FB);
    u16* h2   = (u16*)alloc(FB);

    const int B = 256;
    int Gh = (E + CH - 1) / CH;
    int Gg = (N + 127) / 128;
    int Gwt = (WTN + B - 1) / B;

    k_init<<<1 + Gwt, B, 0, stream>>>(curC, curR, W1, W2, W3, fcW, WTh, WTl, WTN);
    k_partC<<<Gh, B, 0, stream>>>(row, col, E, curC, curR, partC, partR);
    // fused: fillD (blocks [0, 2NB)) + gemm0 (blocks [2NB, 2NB+Gg)) — independent halves
    k_fillDg0<<<2 * NB + Gg, B, 0, stream>>>(partC, partR, curC, curR,
                                             off_in, end_in, off_out, end_out,
                                             csr_src, csr_dst, dinv, NB, N,
                                             x, WTh, WTl, gbuf);

    int G1 = (N + 3) / 4;              // node-blocks per plane (4 waves/block)
    int aggG = 2 * G1;                 // 2 feature-planes fused per dispatch

    // layer 0 (unscaled gbuf: agg0 applies dinv per gathered row)
    k_agg0<<<aggG, B, 0, stream>>>((const uint32*)gbuf, csr_src, off_in, end_in, dinv,
                                   b1, (uint32*)t0, N, G1);
    k_mean<<<aggG, B, 0, stream>>>((const uint32*)t0, csr_dst, off_out, end_out,
                                   (uint32*)h0, N, G1);
    // layer 1
    k_gemm1p<<<Gg, B, 0, stream>>>(h0, WTh + 16384, WTl + 16384, dinv, gbuf, N);
    k_agg<<<aggG, B, 0, stream>>>((const uint32*)gbuf, csr_src, off_in, end_in, dinv,
                                  b2, (uint32*)h1, N, G1);
    // layer 2
    k_gemm1p<<<Gg, B, 0, stream>>>(h1, WTh + 2 * 16384, WTl + 2 * 16384, dinv, gbuf, N);
    k_agg<<<aggG, B, 0, stream>>>((const uint32*)gbuf, csr_src, off_in, end_in, dinv,
                                  b3, (uint32*)h2, N, G1);
    // JK combine + final linear
    k_final<<<Gg, B, 0, stream>>>(h0, h1, h2, jkw,
                                  WTh + 3 * 16384, WTl + 3 * 16384, fcb, outp, N);
}

// Round 7
// 324.687 us; speedup vs baseline: 1.1996x; 1.1996x over previous
//
#include <hip/hip_runtime.h>
#include <stdint.h>

typedef unsigned int  uint32;
typedef unsigned short u16;

typedef short bfx8 __attribute__((ext_vector_type(8)));
typedef float f32x4 __attribute__((ext_vector_type(4)));
typedef uint32 u32x4 __attribute__((ext_vector_type(4)));

#define NBP 256          // padded bucket count (N <= 65536)
#define CH  2048         // edges per partition chunk
#define BS  4608         // fixed slots per bucket (mean 4096, sigma~64 -> 8-sigma margin)

// ---------- bf16 helpers ----------
__device__ __forceinline__ float b2f(u16 u) {
    union { uint32 i; float f; } v; v.i = ((uint32)u) << 16; return v.f;
}
__device__ __forceinline__ u16 f2b(float f) {
    union { float f; uint32 i; } v; v.f = f;
    uint32 u = v.i;
    return (u16)((u + 0x7fffu + ((u >> 16) & 1u)) >> 16);   // RNE
}
__device__ __forceinline__ float blo(uint32 u) {
    union { uint32 i; float f; } v; v.i = u << 16; return v.f;
}
__device__ __forceinline__ float bhi(uint32 u) {
    union { uint32 i; float f; } v; v.i = u & 0xffff0000u; return v.f;
}
__device__ __forceinline__ uint32 packbf(float a, float b) {
    return (uint32)f2b(a) | ((uint32)f2b(b) << 16);
}
__device__ __forceinline__ void splitf(float x, u16& h, u16& l) {
    h = f2b(x);
    l = f2b(x - b2f(h));
}
// accumulate a 16-byte chunk (4 packed bf16-pairs) into 8 fp32 sums
__device__ __forceinline__ void acc4(float* s, u32x4 v) {
    s[0] += blo(v.x); s[1] += bhi(v.x);
    s[2] += blo(v.y); s[3] += bhi(v.y);
    s[4] += blo(v.z); s[5] += bhi(v.z);
    s[6] += blo(v.w); s[7] += bhi(v.w);
}
// fused-scale accumulate: s += d * v
__device__ __forceinline__ void acc4f(float* s, u32x4 v, float d) {
    s[0] = fmaf(blo(v.x), d, s[0]); s[1] = fmaf(bhi(v.x), d, s[1]);
    s[2] = fmaf(blo(v.y), d, s[2]); s[3] = fmaf(bhi(v.y), d, s[3]);
    s[4] = fmaf(blo(v.z), d, s[4]); s[5] = fmaf(bhi(v.z), d, s[5]);
    s[6] = fmaf(blo(v.w), d, s[6]); s[7] = fmaf(bhi(v.w), d, s[7]);
}

// ---------- fused dispatch: partC edge blocks [0,Gh) + weight-split blocks [Gh,..) ----
// Cursors curC/curR are ZERO-BASED counters (hipMemsetAsync'd); base b*BS added at use.
__global__ __launch_bounds__(256) void k_partCW(
    const int* __restrict__ row, const int* __restrict__ col, int E, int Gh,
    int* __restrict__ curC, int* __restrict__ curR,
    uint32* __restrict__ partC, uint32* __restrict__ partR,
    const float* __restrict__ W1, const float* __restrict__ W2,
    const float* __restrict__ W3, const float* __restrict__ fcW,
    u16* __restrict__ WTh, u16* __restrict__ WTl, int WTN) {
    __shared__ uint32 stagedC[CH], stagedR[CH];
    __shared__ int hp[NBP], expk[NBP], curp[NBP], runC[NBP], runR[NBP];
    __shared__ int wsum[4];
    int t = threadIdx.x;

    if ((int)blockIdx.x >= Gh) {
        // ----- weight split half (independent of partC blocks) -----
        int i = ((int)blockIdx.x - Gh) * 256 + t;
        if (i >= WTN) return;
        float w;
        if (i < 3 * 16384) {
            int m = i >> 14, j = i & 16383;     // j = fo*128 + fi
            int fo = j >> 7, fi = j & 127;
            const float* W = (m == 0) ? W1 : (m == 1) ? W2 : W3;
            w = W[fi * 128 + fo];
        } else {
            int j = i - 3 * 16384;
            int fo = j >> 7, fi = j & 127;
            w = fcW[fi * 64 + fo];
        }
        u16 h, l; splitf(w, h, l);
        WTh[i] = h; WTl[i] = l;
        return;
    }

    int lane = t & 63, wid = t >> 6;
    int base = blockIdx.x * CH;
    int n = E - base; if (n > CH) n = CH;

    int er[8], ec[8];
#pragma unroll
    for (int j = 0; j < 8; ++j) {
        int i = t + j * 256;
        if (i < n) { er[j] = row[base + i]; ec[j] = col[base + i]; }
        else er[j] = -1;
    }
    hp[t] = 0;
    __syncthreads();
#pragma unroll
    for (int j = 0; j < 8; ++j) {
        if (er[j] >= 0) {
            atomicAdd(&hp[ec[j] >> 8], 1);
            atomicAdd(&hp[er[j] >> 8], 0x10000);
        }
    }
    __syncthreads();
    int v = hp[t];
    int x = v;
#pragma unroll
    for (int d = 1; d < 64; d <<= 1) {
        int u = __shfl_up(x, d);
        if (lane >= d) x += u;
    }
    if (lane == 63) wsum[wid] = x;
    __syncthreads();
    int add = 0;
    for (int i = 0; i < wid; ++i) add += wsum[i];
    int ex = x + add - v;
    expk[t] = ex;
    curp[t] = ex;
    int vC = v & 0xffff, vR = v >> 16;
    runC[t] = vC ? (t * BS + atomicAdd(&curC[t], vC)) : 0;
    runR[t] = vR ? (t * BS + atomicAdd(&curR[t], vR)) : 0;
    __syncthreads();
#pragma unroll
    for (int j = 0; j < 8; ++j) {
        if (er[j] >= 0) {
            int cb = ec[j] >> 8, rb = er[j] >> 8;
            int pC = atomicAdd(&curp[cb], 1) & 0xffff;
            stagedC[pC] = ((uint32)ec[j] << 16) | (uint32)er[j];
            int pR = atomicAdd(&curp[rb], 0x10000) >> 16;
            stagedR[pR] = ((uint32)er[j] << 16) | (uint32)ec[j];
        }
    }
    __syncthreads();
    for (int i = t; i < n; i += 256) {
        uint32 pv = stagedC[i];
        int b = pv >> 24;
        partC[runC[b] + (i - (expk[b] & 0xffff))] = pv;
    }
    for (int i = t; i < n; i += 256) {
        uint32 pv = stagedR[i];
        int b = pv >> 24;
        partR[runR[b] + (i - (expk[b] >> 16))] = pv;
    }
}

// ---------- fused dispatch: fillD blocks + gemm0 blocks (independent halves) ----------
// fillD part: per-bucket CSR fill + per-node (start,end) + dinv. (cursors are counts)
// gemm0 part: G = A @ W, bf16 out, NO dinv scale (layer-0 agg applies dinv per row).
__global__ __launch_bounds__(256) void k_fillDg0(
    const uint32* __restrict__ partC, const uint32* __restrict__ partR,
    const int* __restrict__ curC, const int* __restrict__ curR,
    int* __restrict__ off_in, int* __restrict__ end_in,
    int* __restrict__ off_out, int* __restrict__ end_out,
    u16* __restrict__ csr_src, u16* __restrict__ csr_dst,
    float* __restrict__ dinv, int NB, int N,
    const float* __restrict__ A, const u16* __restrict__ WTh,
    const u16* __restrict__ WTl, u16* __restrict__ G) {
    __shared__ int cnt[NBP], cur[NBP];
    __shared__ int wsum[4];
    int t = threadIdx.x;

    if ((int)blockIdx.x < 2 * NB) {
        // ----- fillD half -----
        int part = ((int)blockIdx.x >= NB) ? 1 : 0;
        int b = (int)blockIdx.x - part * NB;
        const uint32* arr = part ? partR : partC;
        const int* curA   = part ? curR : curC;
        int* offA         = part ? off_out : off_in;
        int* endA         = part ? end_out : end_in;
        u16* csr          = part ? csr_dst : csr_src;
        int lane = t & 63, wid = t >> 6;
        int base = b * BS, end = base + curA[b];
        cnt[t] = 0;
        __syncthreads();
        for (int i = base + t; i < end; i += 256)
            atomicAdd(&cnt[(arr[i] >> 16) & 255], 1);
        __syncthreads();
        int v = cnt[t];
        int x = v;
#pragma unroll
        for (int d = 1; d < 64; d <<= 1) {
            int u = __shfl_up(x, d);
            if (lane >= d) x += u;
        }
        if (lane == 63) wsum[wid] = x;
        __syncthreads();
        int add = 0;
        for (int i = 0; i < wid; ++i) add += wsum[i];
        int ex = x + add - v;
        cur[t] = ex;
        int node = (b << 8) + t;
        if (node < N) {
            offA[node] = base + ex;
            endA[node] = base + ex + v;
            if (part == 0) dinv[node] = rsqrtf((float)(v + 1));   // in-degree + self loop
        }
        __syncthreads();
        for (int i = base + t; i < end; i += 256) {
            uint32 pv = arr[i];
            int local = (pv >> 16) & 255;
            int pos = atomicAdd(&cur[local], 1);
            csr[base + pos] = (u16)(pv & 0xffffu);
        }
        return;
    }

    // ----- gemm0 half -----
    {
        int gb = (int)blockIdx.x - 2 * NB;
        const int lane = t & 63;
        const int q = lane >> 4, l = lane & 15;
        int rbase = gb * 128 + (t >> 6) * 32;
        if (rbase >= N) return;
        int r0 = rbase + l;      if (r0 >= N) r0 = N - 1;
        int r1 = rbase + 16 + l; if (r1 >= N) r1 = N - 1;

        f32x4 acc[2][8];
#pragma unroll
        for (int i = 0; i < 2; ++i)
#pragma unroll
            for (int j = 0; j < 8; ++j) acc[i][j] = (f32x4){0.f, 0.f, 0.f, 0.f};

#pragma unroll
        for (int kc = 0; kc < 4; ++kc) {
            int k0 = kc * 32 + q * 8;
            bfx8 ah0, ah1;
            {
                f32x4 a = *(const f32x4*)(A + (size_t)r0 * 128 + k0);
                f32x4 b = *(const f32x4*)(A + (size_t)r0 * 128 + k0 + 4);
                float xx[8] = {a[0], a[1], a[2], a[3], b[0], b[1], b[2], b[3]};
#pragma unroll
                for (int j = 0; j < 8; ++j) ah0[j] = (short)f2b(xx[j]);
            }
            {
                f32x4 a = *(const f32x4*)(A + (size_t)r1 * 128 + k0);
                f32x4 b = *(const f32x4*)(A + (size_t)r1 * 128 + k0 + 4);
                float xx[8] = {a[0], a[1], a[2], a[3], b[0], b[1], b[2], b[3]};
#pragma unroll
                for (int j = 0; j < 8; ++j) ah1[j] = (short)f2b(xx[j]);
            }
#pragma unroll
            for (int ct = 0; ct < 8; ++ct) {
                bfx8 bh = *(const bfx8*)(WTh + (ct * 16 + l) * 128 + k0);
                bfx8 bl = *(const bfx8*)(WTl + (ct * 16 + l) * 128 + k0);
                acc[0][ct] = __builtin_amdgcn_mfma_f32_16x16x32_bf16(ah0, bh, acc[0][ct], 0, 0, 0);
                acc[0][ct] = __builtin_amdgcn_mfma_f32_16x16x32_bf16(ah0, bl, acc[0][ct], 0, 0, 0);
                acc[1][ct] = __builtin_amdgcn_mfma_f32_16x16x32_bf16(ah1, bh, acc[1][ct], 0, 0, 0);
                acc[1][ct] = __builtin_amdgcn_mfma_f32_16x16x32_bf16(ah1, bl, acc[1][ct], 0, 0, 0);
            }
        }
#pragma unroll
        for (int rs = 0; rs < 2; ++rs) {
#pragma unroll
            for (int rr = 0; rr < 4; ++rr) {
                int rw = rbase + rs * 16 + q * 4 + rr;
                if (rw < N) {
#pragma unroll
                    for (int ct = 0; ct < 8; ++ct)
                        G[(size_t)rw * 128 + ct * 16 + l] = f2b(acc[rs][ct][rr]);
                }
            }
        }
    }
}

// ---------- gemm, single bf16-plane A: G = (A @ W) * dinv, bf16 out ----------
__global__ __launch_bounds__(256) void k_gemm1p(
    const u16* __restrict__ Ah,
    const u16* __restrict__ WTh, const u16* __restrict__ WTl,
    const float* __restrict__ dinv, u16* __restrict__ G, int M) {
    const int lane = threadIdx.x & 63;
    const int q = lane >> 4, l = lane & 15;
    int rbase = blockIdx.x * 128 + (threadIdx.x >> 6) * 32;
    if (rbase >= M) return;
    int r0 = rbase + l;      if (r0 >= M) r0 = M - 1;
    int r1 = rbase + 16 + l; if (r1 >= M) r1 = M - 1;

    f32x4 acc[2][8];
#pragma unroll
    for (int i = 0; i < 2; ++i)
#pragma unroll
        for (int j = 0; j < 8; ++j) acc[i][j] = (f32x4){0.f, 0.f, 0.f, 0.f};

#pragma unroll
    for (int kc = 0; kc < 4; ++kc) {
        int k0 = kc * 32 + q * 8;
        bfx8 ah0 = *(const bfx8*)(Ah + (size_t)r0 * 128 + k0);
        bfx8 ah1 = *(const bfx8*)(Ah + (size_t)r1 * 128 + k0);
#pragma unroll
        for (int ct = 0; ct < 8; ++ct) {
            bfx8 bh = *(const bfx8*)(WTh + (ct * 16 + l) * 128 + k0);
            bfx8 bl = *(const bfx8*)(WTl + (ct * 16 + l) * 128 + k0);
            acc[0][ct] = __builtin_amdgcn_mfma_f32_16x16x32_bf16(ah0, bh, acc[0][ct], 0, 0, 0);
            acc[0][ct] = __builtin_amdgcn_mfma_f32_16x16x32_bf16(ah0, bl, acc[0][ct], 0, 0, 0);
            acc[1][ct] = __builtin_amdgcn_mfma_f32_16x16x32_bf16(ah1, bh, acc[1][ct], 0, 0, 0);
            acc[1][ct] = __builtin_amdgcn_mfma_f32_16x16x32_bf16(ah1, bl, acc[1][ct], 0, 0, 0);
        }
    }
#pragma unroll
    for (int rs = 0; rs < 2; ++rs) {
#pragma unroll
        for (int rr = 0; rr < 4; ++rr) {
            int rw = rbase + rs * 16 + q * 4 + rr;
            if (rw < M) {
                float dv = dinv[rw];
#pragma unroll
                for (int ct = 0; ct < 8; ++ct)
                    G[(size_t)rw * 128 + ct * 16 + l] = f2b(acc[rs][ct][rr] * dv);
            }
        }
    }
}

// ---------- layer-0 GCN aggregate: UNSCALED table, per-row dinv via fmac ----------
__global__ __launch_bounds__(256) void k_agg0(
    const u32x4* __restrict__ g4, const u16* __restrict__ csr,
    const int* __restrict__ off, const int* __restrict__ endo,
    const float* __restrict__ dinv,
    const float* __restrict__ bias, u32x4* __restrict__ outH4, int n) {
    int w = (blockIdx.x * 256 + threadIdx.x) >> 6;
    if (w >= n) return;
    int lane = threadIdx.x & 63;
    int gq = lane >> 4, c = lane & 15;
    float s[8];
#pragma unroll
    for (int k = 0; k < 8; ++k) s[k] = 0.f;
    int e = off[w], e1 = endo[w];
    for (; e + 16 <= e1; e += 16) {
        int ix[4];
#pragma unroll
        for (int j = 0; j < 4; ++j) ix[j] = csr[e + j * 4 + gq];
        u32x4 vv[4];
        float dd[4];
#pragma unroll
        for (int j = 0; j < 4; ++j) { vv[j] = g4[(size_t)ix[j] * 16 + c]; dd[j] = dinv[ix[j]]; }
#pragma unroll
        for (int j = 0; j < 4; ++j) acc4f(s, vv[j], dd[j]);
    }
    for (; e < e1; e += 4) {
        int idx = e + gq;
        if (idx < e1) {
            int ii = csr[idx];
            acc4f(s, g4[(size_t)ii * 16 + c], dinv[ii]);
        }
    }
#pragma unroll
    for (int k = 0; k < 8; ++k) {
        s[k] += __shfl_xor(s[k], 16);
        s[k] += __shfl_xor(s[k], 32);
    }
    if (lane < 16) {
        float dc = dinv[w];
        u32x4 sv = g4[(size_t)w * 16 + lane];          // self term, scale dc
        acc4f(s, sv, dc);
        const f32x4* B4 = (const f32x4*)bias;
        f32x4 ba = B4[lane * 2], bb = B4[lane * 2 + 1];
        float o[8];
#pragma unroll
        for (int k = 0; k < 4; ++k) o[k] = fmaxf(fmaf(s[k], dc, ba[k]), 0.f);
#pragma unroll
        for (int k = 0; k < 4; ++k) o[4 + k] = fmaxf(fmaf(s[4 + k], dc, bb[k]), 0.f);
        u32x4 ov;
        ov.x = packbf(o[0], o[1]); ov.y = packbf(o[2], o[3]);
        ov.z = packbf(o[4], o[5]); ov.w = packbf(o[6], o[7]);
        outH4[(size_t)w * 16 + lane] = ov;
    }
}

// ---------- GCN aggregate (layers 1-2): PRESCALED table ----------
__global__ __launch_bounds__(256) void k_agg(
    const u32x4* __restrict__ g4, const u16* __restrict__ csr,
    const int* __restrict__ off, const int* __restrict__ endo,
    const float* __restrict__ dinv,
    const float* __restrict__ bias, u32x4* __restrict__ outH4, int n) {
    int w = (blockIdx.x * 256 + threadIdx.x) >> 6;
    if (w >= n) return;
    int lane = threadIdx.x & 63;
    int gq = lane >> 4, c = lane & 15;
    float s[8];
#pragma unroll
    for (int k = 0; k < 8; ++k) s[k] = 0.f;
    int e = off[w], e1 = endo[w];
    for (; e + 16 <= e1; e += 16) {
        int ix[4];
#pragma unroll
        for (int j = 0; j < 4; ++j) ix[j] = csr[e + j * 4 + gq];
        u32x4 vv[4];
#pragma unroll
        for (int j = 0; j < 4; ++j) vv[j] = g4[(size_t)ix[j] * 16 + c];
#pragma unroll
        for (int j = 0; j < 4; ++j) acc4(s, vv[j]);
    }
    for (; e < e1; e += 4) {
        int idx = e + gq;
        if (idx < e1) {
            int ii = csr[idx];
            acc4(s, g4[(size_t)ii * 16 + c]);
        }
    }
#pragma unroll
    for (int k = 0; k < 8; ++k) {
        s[k] += __shfl_xor(s[k], 16);
        s[k] += __shfl_xor(s[k], 32);
    }
    if (lane < 16) {
        u32x4 sv = g4[(size_t)w * 16 + lane];          // self term (prescaled)
        acc4(s, sv);
        float dc = dinv[w];
        const f32x4* B4 = (const f32x4*)bias;
        f32x4 ba = B4[lane * 2], bb = B4[lane * 2 + 1];
        float o[8];
#pragma unroll
        for (int k = 0; k < 4; ++k) o[k] = fmaxf(fmaf(s[k], dc, ba[k]), 0.f);
#pragma unroll
        for (int k = 0; k < 4; ++k) o[4 + k] = fmaxf(fmaf(s[4 + k], dc, bb[k]), 0.f);
        u32x4 ov;
        ov.x = packbf(o[0], o[1]); ov.y = packbf(o[2], o[3]);
        ov.z = packbf(o[4], o[5]); ov.w = packbf(o[6], o[7]);
        outH4[(size_t)w * 16 + lane] = ov;
    }
}

// ---------- neighbor mean, wave-per-node, bf16 out ----------
__global__ __launch_bounds__(256) void k_mean(
    const u32x4* __restrict__ h4, const u16* __restrict__ csr,
    const int* __restrict__ off, const int* __restrict__ endo,
    u32x4* __restrict__ outH4, int n) {
    int w = (blockIdx.x * 256 + threadIdx.x) >> 6;
    if (w >= n) return;
    int lane = threadIdx.x & 63;
    int gq = lane >> 4, c = lane & 15;
    float s[8];
#pragma unroll
    for (int k = 0; k < 8; ++k) s[k] = 0.f;
    int e = off[w], e1 = endo[w];
    int d = e1 - e;
    for (; e + 16 <= e1; e += 16) {
        int ix[4];
#pragma unroll
        for (int j = 0; j < 4; ++j) ix[j] = csr[e + j * 4 + gq];
        u32x4 vv[4];
#pragma unroll
        for (int j = 0; j < 4; ++j) vv[j] = h4[(size_t)ix[j] * 16 + c];
#pragma unroll
        for (int j = 0; j < 4; ++j) acc4(s, vv[j]);
    }
    for (; e < e1; e += 4) {
        int idx = e + gq;
        if (idx < e1) {
            int ii = csr[idx];
            acc4(s, h4[(size_t)ii * 16 + c]);
        }
    }
#pragma unroll
    for (int k = 0; k < 8; ++k) {
        s[k] += __shfl_xor(s[k], 16);
        s[k] += __shfl_xor(s[k], 32);
    }
    if (lane < 16) {
        u32x4 ov;
        if (d > 0) {
            float inv = 1.f / (float)d;
            ov.x = packbf(s[0] * inv, s[1] * inv);
            ov.y = packbf(s[2] * inv, s[3] * inv);
            ov.z = packbf(s[4] * inv, s[5] * inv);
            ov.w = packbf(s[6] * inv, s[7] * inv);
        } else {
            ov = h4[(size_t)w * 16 + lane];            // degree 0: own feature
        }
        outH4[(size_t)w * 16 + lane] = ov;
    }
}

// ---------- final: out = (w0*h0 + w1*h1 + w2*h2) @ fcW + fc_b ----------
__global__ __launch_bounds__(256) void k_final(
    const u16* __restrict__ h0, const u16* __restrict__ h1,
    const u16* __restrict__ h2, const float* __restrict__ jkw,
    const u16* __restrict__ fcWTh, const u16* __restrict__ fcWTl,
    const float* __restrict__ fcb, float* __restrict__ out, int M) {
    float a0 = jkw[0], a1 = jkw[1], a2 = jkw[2];
    float mx = fmaxf(a0, fmaxf(a1, a2));
    float e0 = expf(a0 - mx), e1 = expf(a1 - mx), e2 = expf(a2 - mx);
    float inv = 1.f / (e0 + e1 + e2);
    float w0 = e0 * inv, w1 = e1 * inv, w2 = e2 * inv;

    const int lane = threadIdx.x & 63;
    const int q = lane >> 4, l = lane & 15;
    int rbase = blockIdx.x * 128 + (threadIdx.x >> 6) * 32;
    if (rbase >= M) return;
    int r0 = rbase + l;      if (r0 >= M) r0 = M - 1;
    int r1 = rbase + 16 + l; if (r1 >= M) r1 = M - 1;

    f32x4 acc[2][4];
#pragma unroll
    for (int i = 0; i < 2; ++i)
#pragma unroll
        for (int j = 0; j < 4; ++j) acc[i][j] = (f32x4){0.f, 0.f, 0.f, 0.f};

    union U8 { bfx8 v; u16 u[8]; };

#pragma unroll
    for (int kc = 0; kc < 4; ++kc) {
        int k0 = kc * 32 + q * 8;
        bfx8 ah[2];
        const int rr2[2] = {r0, r1};
#pragma unroll
        for (int half = 0; half < 2; ++half) {
            size_t o = (size_t)rr2[half] * 128 + k0;
            U8 x0, x1, x2, rh;
            x0.v = *(const bfx8*)(h0 + o);
            x1.v = *(const bfx8*)(h1 + o);
            x2.v = *(const bfx8*)(h2 + o);
#pragma unroll
            for (int j = 0; j < 8; ++j) {
                float c = w0 * b2f(x0.u[j]) + w1 * b2f(x1.u[j]) + w2 * b2f(x2.u[j]);
                rh.u[j] = f2b(c);
            }
            ah[half] = rh.v;
        }
#pragma unroll
        for (int ct = 0; ct < 4; ++ct) {
            bfx8 bh = *(const bfx8*)(fcWTh + (ct * 16 + l) * 128 + k0);
            bfx8 bl = *(const bfx8*)(fcWTl + (ct * 16 + l) * 128 + k0);
#pragma unroll
            for (int half = 0; half < 2; ++half) {
                acc[half][ct] = __builtin_amdgcn_mfma_f32_16x16x32_bf16(ah[half], bh, acc[half][ct], 0, 0, 0);
                acc[half][ct] = __builtin_amdgcn_mfma_f32_16x16x32_bf16(ah[half], bl, acc[half][ct], 0, 0, 0);
            }
        }
    }
#pragma unroll
    for (int rs = 0; rs < 2; ++rs) {
#pragma unroll
        for (int rr = 0; rr < 4; ++rr) {
            int rw = rbase + rs * 16 + q * 4 + rr;
            if (rw < M) {
#pragma unroll
                for (int ct = 0; ct < 4; ++ct) {
                    int cc = ct * 16 + l;
                    out[(size_t)rw * 64 + cc] = acc[rs][ct][rr] + fcb[cc];
                }
            }
        }
    }
}

extern "C" void kernel_launch(void* const* d_in, const int* in_sizes, int n_in,
                              void* d_out, int out_size, void* d_ws, size_t ws_size,
                              hipStream_t stream) {
    const int N = in_sizes[0] / 128;   // 50000
    const int E = in_sizes[1] / 2;     // 800000
    const int NB = (N + 255) >> 8;     // 196 buckets

    const float* x    = (const float*)d_in[0];
    const int* row    = (const int*)d_in[1];
    const int* col    = row + E;
    const float* W1   = (const float*)d_in[2];
    const float* b1   = (const float*)d_in[3];
    const float* W2   = (const float*)d_in[4];
    const float* b2   = (const float*)d_in[5];
    const float* W3   = (const float*)d_in[6];
    const float* b3   = (const float*)d_in[7];
    const float* jkw  = (const float*)d_in[8];
    const float* fcW  = (const float*)d_in[9];
    const float* fcb  = (const float*)d_in[10];
    float* outp       = (float*)d_out;

    char* ws = (char*)d_ws;
    size_t off = 0;
    auto alloc = [&](size_t bytes) -> char* {
        char* p = ws + off;
        off += (bytes + 255) & ~(size_t)255;
        return p;
    };
    int* curC   = (int*)alloc((size_t)NBP * sizeof(int));
    int* curR   = (int*)alloc((size_t)NBP * sizeof(int));
    int* off_in  = (int*)alloc((size_t)N * sizeof(int));
    int* end_in  = (int*)alloc((size_t)N * sizeof(int));
    int* off_out = (int*)alloc((size_t)N * sizeof(int));
    int* end_out = (int*)alloc((size_t)N * sizeof(int));
    uint32* partC = (uint32*)alloc((size_t)NBP * BS * sizeof(uint32));
    uint32* partR = (uint32*)alloc((size_t)NBP * BS * sizeof(uint32));
    u16* csr_src = (u16*)alloc((size_t)NBP * BS * sizeof(u16));
    u16* csr_dst = (u16*)alloc((size_t)NBP * BS * sizeof(u16));
    float* dinv  = (float*)alloc((size_t)N * sizeof(float));
    const int WTN = 3 * 16384 + 8192;
    u16* WTh = (u16*)alloc((size_t)WTN * sizeof(u16));
    u16* WTl = (u16*)alloc((size_t)WTN * sizeof(u16));
    size_t FB = (size_t)N * 128 * sizeof(u16);
    u16* gbuf = (u16*)alloc(FB);
    u16* t0   = (u16*)alloc(FB);
    u16* h0   = (u16*)alloc(FB);
    u16* h1   = (u16*)alloc(FB);
    u16* h2   = (u16*)alloc(FB);

    const int B = 256;
    int Gh = (E + CH - 1) / CH;
    int Gg = (N + 127) / 128;
    int Gwt = (WTN + B - 1) / B;

    // zero-based bucket cursors (curC, curR are adjacent 256B-aligned allocs)
    hipMemsetAsync(curC, 0, 2 * NBP * sizeof(int), stream);
    // fused: partC edge blocks [0,Gh) + weight-split blocks [Gh, Gh+Gwt)
    k_partCW<<<Gh + Gwt, B, 0, stream>>>(row, col, E, Gh, curC, curR, partC, partR,
                                         W1, W2, W3, fcW, WTh, WTl, WTN);
    // fused: fillD (blocks [0, 2NB)) + gemm0 (blocks [2NB, 2NB+Gg)) — independent halves
    k_fillDg0<<<2 * NB + Gg, B, 0, stream>>>(partC, partR, curC, curR,
                                             off_in, end_in, off_out, end_out,
                                             csr_src, csr_dst, dinv, NB, N,
                                             x, WTh, WTl, gbuf);

    int aggG = (N + 3) / 4;            // 4 waves/block, 1 node/wave

    // layer 0 (unscaled gbuf: agg0 applies dinv per gathered row)
    k_agg0<<<aggG, B, 0, stream>>>((const u32x4*)gbuf, csr_src, off_in, end_in, dinv,
                                   b1, (u32x4*)t0, N);
    k_mean<<<aggG, B, 0, stream>>>((const u32x4*)t0, csr_dst, off_out, end_out,
                                   (u32x4*)h0, N);
    // layer 1
    k_gemm1p<<<Gg, B, 0, stream>>>(h0, WTh + 16384, WTl + 16384, dinv, gbuf, N);
    k_agg<<<aggG, B, 0, stream>>>((const u32x4*)gbuf, csr_src, off_in, end_in, dinv,
                                  b2, (u32x4*)h1, N);
    // layer 2
    k_gemm1p<<<Gg, B, 0, stream>>>(h1, WTh + 2 * 16384, WTl + 2 * 16384, dinv, gbuf, N);
    k_agg<<<aggG, B, 0, stream>>>((const u32x4*)gbuf, csr_src, off_in, end_in, dinv,
                                  b3, (u32x4*)h2, N);
    // JK combine + final linear
    k_final<<<Gg, B, 0, stream>>>(h0, h1, h2, jkw,
                                  WTh + 3 * 16384, WTl + 3 * 16384, fcb, outp, N);
}